// Round 9
// baseline (103.815 us; speedup 1.0000x reference)
//
#include <hip/hip_runtime.h>
#include <math.h>

// HoltWintersDecomposition: x (8192, 2048) f32, sequential per-row recurrence.
// r9: spread to 256 CUs (32 rows/block, producer wave half-masked) + drop
// Newton iterations (v_rcp_f32 is ~1 ulp; chain 56 -> ~40 cy/step).
//   wave 0 (producer): lanes 0..31 = rows; loads own row's x directly from
//     global (register chunk double-buffer, 2-chunk prefetch distance);
//     writes l/s/y as ds_write_b128 per 4 steps.
//   wave 1 (consumer): LDS->global transposed stores, full 64B lines.
// One barrier per 64-step tile; x prefetch issued only AFTER barriers so the
// vmcnt(0) barrier-drain never waits on a fresh load.
// Parallel-in-time (r6) is mathematically broken here (s ~ 20*EPS; EPS breaks
// the scale invariance) -- the serial chain stands.

constexpr int   T    = 2048;
constexpr int   B    = 8192;
constexpr int   RPB  = 32;        // rows per block
constexpr int   CH   = 16;        // steps per x register chunk
constexpr int   NCH  = T / CH;    // 128 chunks
constexpr int   TT   = 64;        // steps per LDS tile (4 chunks)
constexpr int   NTI  = T / TT;    // 32 tiles
constexpr int   LSX  = 68;        // LDS stride words: 272B rows, 16B-aligned
constexpr float EPS  = 1e-8f;

__global__ __launch_bounds__(128, 1)
void hw_kernel(const float* __restrict__ x,
               const float* __restrict__ pla,
               const float* __restrict__ plg,
               float* __restrict__ out)
{
    __shared__ alignas(16) float LT[2][RPB][LSX];
    __shared__ alignas(16) float ST[2][RPB][LSX];
    __shared__ alignas(16) float YT[2][RPB][LSX];

    const int tid  = threadIdx.x;
    const int wid  = tid >> 6;        // 0 = producer, 1 = consumer
    const int lane = tid & 63;
    const int row0 = blockIdx.x * RPB;

    const float alpha = 1.0f / (1.0f + expf(-pla[0]));
    const float gamma = 1.0f / (1.0f + expf(-plg[0]));
    const float oma = 1.0f - alpha, omg = 1.0f - gamma;

    float* __restrict__ lout = out;
    float* __restrict__ sout = out + (size_t)B * T;
    float* __restrict__ yout = out + (size_t)2 * B * T;

    if (wid == 0) {
        // ================= producer =================
        const bool act = lane < RPB;
        const float* __restrict__ xrow = x + (size_t)(row0 + (act ? lane : 0)) * T;

        float lp = 0.0f, sp = 1.0f;
        float4 XA[4], XB[4];

        auto loadX = [&](float4* Xb, int c) {
            const float* p = xrow + c * CH;
            #pragma unroll
            for (int k = 0; k < 4; ++k)
                Xb[k] = *reinterpret_cast<const float4*>(p + 4 * k);
        };

        auto do_step = [&](float xt, float& lo, float& so, float& yo) {
            const float rs = __builtin_amdgcn_rcpf(sp + EPS);
            const float lt = __builtin_fmaf(oma, lp, (alpha * xt) * rs);
            const float rl = __builtin_amdgcn_rcpf(lt + EPS);
            const float st = __builtin_fmaf(omg, sp, (gamma * xt) * rl);
            yo = xt * __builtin_amdgcn_rcpf(__builtin_fmaf(lt, st, EPS));
            lo = lt; so = st;
            lp = lt; sp = st;
        };

        // one 16-step chunk: compute + LDS b128 writes
        auto chunk = [&](const float4* Xb, int c, bool first) {
            const int bsel = (c >> 2) & 1;
            const int off  = (c & 3) * CH;
            #pragma unroll
            for (int q = 0; q < 4; ++q) {
                const float4 xv = Xb[q];
                float4 lv, sv, yv;
                if (first && q == 0) {
                    // t == 0: l0 = x0, s0 = 1, y0 = x0/(x0+eps)
                    lv.x = xv.x; sv.x = 1.0f;
                    yv.x = xv.x * __builtin_amdgcn_rcpf(xv.x + EPS);
                    lp = xv.x; sp = 1.0f;
                    do_step(xv.y, lv.y, sv.y, yv.y);
                    do_step(xv.z, lv.z, sv.z, yv.z);
                    do_step(xv.w, lv.w, sv.w, yv.w);
                } else {
                    do_step(xv.x, lv.x, sv.x, yv.x);
                    do_step(xv.y, lv.y, sv.y, yv.y);
                    do_step(xv.z, lv.z, sv.z, yv.z);
                    do_step(xv.w, lv.w, sv.w, yv.w);
                }
                *reinterpret_cast<float4*>(&LT[bsel][lane][off + 4 * q]) = lv;
                *reinterpret_cast<float4*>(&ST[bsel][lane][off + 4 * q]) = sv;
                *reinterpret_cast<float4*>(&YT[bsel][lane][off + 4 * q]) = yv;
            }
        };

        if (act) { loadX(XA, 0); loadX(XB, 1); }
        if (act) chunk(XA, 0, true);
        if (act) loadX(XA, 2);

        // chunks 1..126 in pairs; barrier after every chunk c with c%4==3
        #pragma unroll 1
        for (int c = 1; c < NCH - 1; c += 2) {
            if (act) chunk(XB, c, false);
            if ((c & 3) == 3) __syncthreads();
            if (act) {
                loadX(XB, (c + 2 < NCH) ? c + 2 : NCH - 1);
                chunk(XA, c + 1, false);
                loadX(XA, (c + 3 < NCH) ? c + 3 : NCH - 1);
            }
        }
        if (act) chunk(XB, NCH - 1, false);
        __syncthreads();                         // 32nd barrier (tile 31 ready)
    } else {
        // ================= consumer =================
        const int cr = lane >> 4;          // 0..3
        const int cc = (lane & 15) << 2;   // 0,4,...,60

        auto store_tile = [&](int m, int itlo, int ithi) {
            const int bsel = m & 1;
            const int t0 = m * TT;
            for (int it = itlo; it < ithi; ++it) {
                const int r = 4 * it + cr;
                const size_t g = (size_t)(row0 + r) * T + t0 + cc;
                const float4 vl = *reinterpret_cast<const float4*>(&LT[bsel][r][cc]);
                const float4 vs = *reinterpret_cast<const float4*>(&ST[bsel][r][cc]);
                const float4 vy = *reinterpret_cast<const float4*>(&YT[bsel][r][cc]);
                *reinterpret_cast<float4*>(&lout[g]) = vl;
                *reinterpret_cast<float4*>(&sout[g]) = vs;
                *reinterpret_cast<float4*>(&yout[g]) = vy;
            }
        };

        #pragma unroll 1
        for (int k = 0; k < NTI; ++k) {
            if (k > 0) store_tile(k - 1, 0, 8);
            __syncthreads();
        }
    }

    // epilogue: tile 31 (buffer 1), both waves split the 8 store groups
    {
        const int cr = lane >> 4;
        const int cc = (lane & 15) << 2;
        const int t0 = (NTI - 1) * TT;
        for (int it = wid * 4; it < wid * 4 + 4; ++it) {
            const int r = 4 * it + cr;
            const size_t g = (size_t)(row0 + r) * T + t0 + cc;
            const float4 vl = *reinterpret_cast<const float4*>(&LT[1][r][cc]);
            const float4 vs = *reinterpret_cast<const float4*>(&ST[1][r][cc]);
            const float4 vy = *reinterpret_cast<const float4*>(&YT[1][r][cc]);
            *reinterpret_cast<float4*>(&lout[g]) = vl;
            *reinterpret_cast<float4*>(&sout[g]) = vs;
            *reinterpret_cast<float4*>(&yout[g]) = vy;
        }
    }
}

extern "C" void kernel_launch(void* const* d_in, const int* in_sizes, int n_in,
                              void* d_out, int out_size, void* d_ws, size_t ws_size,
                              hipStream_t stream) {
    const float* x   = (const float*)d_in[0];
    const float* pla = (const float*)d_in[1];
    const float* plg = (const float*)d_in[2];
    float* out = (float*)d_out;

    dim3 grid(B / RPB);    // 256 blocks -> one producer/consumer pair per CU
    dim3 block(128);       // wave 0 = producer (32 rows), wave 1 = consumer
    hw_kernel<<<grid, block, 0, stream>>>(x, pla, plg, out);
}

// Round 10
// 96.372 us; speedup vs baseline: 1.0772x; 1.0772x over previous
//
#include <hip/hip_runtime.h>
#include <math.h>

// HoltWintersDecomposition: x (8192, 2048) f32, sequential per-row recurrence.
// r10 = r8's wave-role discipline + r9's 256-CU spread:
//   - 256 blocks x 32 rows/block: every CU gets one producer/consumer pair;
//     per-CU store traffic halves vs r8 (consumer was r8's critical path:
//     64KB/tile x 32 tiles / 117us = 17.5 GB/s/CU ~ saturated).
//   - producer wave touches ONLY LDS (r9 lesson: __syncthreads drains vmcnt(0),
//     so any producer-side global prefetch gets its latency exposed at every
//     tile barrier). Consumer stages x global->LDS and stores l/s/y LDS->global
//     as full 64B lines.
//   - raw v_rcp_f32, no Newton (r9 evidence: absmax 16384 unchanged).
// Parallel-in-time (r6) is mathematically broken here (s ~ 20*EPS; EPS breaks
// the scale invariance) -- the serial chain stands.

constexpr int   T    = 2048;
constexpr int   B    = 8192;
constexpr int   RPB  = 32;        // rows per block
constexpr int   TT   = 64;        // steps per tile
constexpr int   NTI  = T / TT;    // 32 tiles
constexpr int   LSX  = 68;        // LDS stride words: 272B rows, 16B-aligned
constexpr float EPS  = 1e-8f;

__global__ __launch_bounds__(128, 1)
void hw_kernel(const float* __restrict__ x,
               const float* __restrict__ pla,
               const float* __restrict__ plg,
               float* __restrict__ out)
{
    __shared__ alignas(16) float XT[2][RPB][LSX];
    __shared__ alignas(16) float LT[2][RPB][LSX];
    __shared__ alignas(16) float ST[2][RPB][LSX];
    __shared__ alignas(16) float YT[2][RPB][LSX];

    const int tid  = threadIdx.x;
    const int wid  = tid >> 6;        // 0 = producer, 1 = consumer
    const int lane = tid & 63;
    const int row0 = blockIdx.x * RPB;

    const float alpha = 1.0f / (1.0f + expf(-pla[0]));
    const float gamma = 1.0f / (1.0f + expf(-plg[0]));
    const float oma = 1.0f - alpha, omg = 1.0f - gamma;

    float* __restrict__ lout = out;
    float* __restrict__ sout = out + (size_t)B * T;
    float* __restrict__ yout = out + (size_t)2 * B * T;

    // consumer lane mapping: lane -> (row subgroup, col4)
    const int cr = lane >> 4;          // 0..3
    const int cc = (lane & 15) << 2;   // 0,4,...,60

    float lp = 0.0f, sp = 1.0f;        // producer chain state

    // ---- consumer: coalesced global->LDS x tile staging (8 rows-groups)
    auto load_x_tile = [&](int k) {
        const int bsel = k & 1;
        const int t1 = k * TT;
        #pragma unroll
        for (int it = 0; it < 8; ++it) {
            const int r = 4 * it + cr;
            const float4 v = *reinterpret_cast<const float4*>(
                &x[(size_t)(row0 + r) * T + t1 + cc]);
            *reinterpret_cast<float4*>(&XT[bsel][r][cc]) = v;
        }
    };

    // ---- consumer: LDS->global transposed stores (full 64B lines)
    auto store_tile = [&](int m, int itlo, int ithi) {
        const int bsel = m & 1;
        const int t0 = m * TT;
        for (int it = itlo; it < ithi; ++it) {
            const int r = 4 * it + cr;
            const size_t g = (size_t)(row0 + r) * T + t0 + cc;
            const float4 vl = *reinterpret_cast<const float4*>(&LT[bsel][r][cc]);
            const float4 vs = *reinterpret_cast<const float4*>(&ST[bsel][r][cc]);
            const float4 vy = *reinterpret_cast<const float4*>(&YT[bsel][r][cc]);
            *reinterpret_cast<float4*>(&lout[g]) = vl;
            *reinterpret_cast<float4*>(&sout[g]) = vs;
            *reinterpret_cast<float4*>(&yout[g]) = vy;
        }
    };

    // ---- producer: one recurrence step (raw v_rcp_f32, no Newton)
    auto do_step = [&](float xt, float& lo, float& so, float& yo) {
        const float rs = __builtin_amdgcn_rcpf(sp + EPS);
        const float lt = __builtin_fmaf(oma, lp, (alpha * xt) * rs);
        const float rl = __builtin_amdgcn_rcpf(lt + EPS);
        const float st = __builtin_fmaf(omg, sp, (gamma * xt) * rl);
        yo = xt * __builtin_amdgcn_rcpf(__builtin_fmaf(lt, st, EPS));
        lo = lt; so = st;
        lp = lt; sp = st;
    };

    // ---- producer: one 64-step tile, LDS-only I/O, 4 steps per b128 group
    auto compute_tile = [&](int k, bool first) {
        const int bsel = k & 1;
        #pragma unroll
        for (int g = 0; g < 16; ++g) {
            const float4 xv = *reinterpret_cast<const float4*>(&XT[bsel][lane][4 * g]);
            float4 lv, sv, yv;
            if (first && g == 0) {
                // t == 0: l0 = x0, s0 = 1, y0 = x0/(x0 + eps)
                lv.x = xv.x; sv.x = 1.0f;
                yv.x = xv.x * __builtin_amdgcn_rcpf(xv.x + EPS);
                lp = xv.x; sp = 1.0f;
                do_step(xv.y, lv.y, sv.y, yv.y);
                do_step(xv.z, lv.z, sv.z, yv.z);
                do_step(xv.w, lv.w, sv.w, yv.w);
            } else {
                do_step(xv.x, lv.x, sv.x, yv.x);
                do_step(xv.y, lv.y, sv.y, yv.y);
                do_step(xv.z, lv.z, sv.z, yv.z);
                do_step(xv.w, lv.w, sv.w, yv.w);
            }
            *reinterpret_cast<float4*>(&LT[bsel][lane][4 * g]) = lv;
            *reinterpret_cast<float4*>(&ST[bsel][lane][4 * g]) = sv;
            *reinterpret_cast<float4*>(&YT[bsel][lane][4 * g]) = yv;
        }
    };

    // ---- pipeline: one barrier per tile
    if (wid == 1) load_x_tile(0);
    __syncthreads();

    for (int k = 0; k < NTI; ++k) {
        if (wid == 0) {
            if (lane < RPB) compute_tile(k, k == 0);
        } else {
            if (k + 1 < NTI) load_x_tile(k + 1);
            if (k > 0)       store_tile(k - 1, 0, 8);
        }
        __syncthreads();
    }

    // epilogue: tile 31 (buffer 1), both waves split the 8 store groups
    store_tile(NTI - 1, wid * 4, wid * 4 + 4);
}

extern "C" void kernel_launch(void* const* d_in, const int* in_sizes, int n_in,
                              void* d_out, int out_size, void* d_ws, size_t ws_size,
                              hipStream_t stream) {
    const float* x   = (const float*)d_in[0];
    const float* pla = (const float*)d_in[1];
    const float* plg = (const float*)d_in[2];
    float* out = (float*)d_out;

    dim3 grid(B / RPB);    // 256 blocks -> one producer/consumer pair per CU
    dim3 block(128);       // wave 0 = producer (32 rows), wave 1 = consumer
    hw_kernel<<<grid, block, 0, stream>>>(x, pla, plg, out);
}

// Round 11
// 87.335 us; speedup vs baseline: 1.1887x; 1.1035x over previous
//
#include <hip/hip_runtime.h>
#include <math.h>

// HoltWintersDecomposition: x (8192, 2048) f32, sequential per-row recurrence.
// r11 = r10 + x moved off the chain into producer registers:
//   - 256 blocks x 32 rows/block (one producer/consumer wave pair per CU).
//   - producer: lanes 0..31 = rows. Prefetches the NEXT tile's x (16 x float4,
//     own row) right after each barrier -> consumed one full tile (~2600 cy)
//     later, so load latency AND the barrier vmcnt(0) drain (r9 lesson: 1-chunk
//     distance stalls; 1-tile distance is safe) are covered. The 64-step chain
//     reads x from REGISTERS (r10's 16 ds_read_b128/tile each cost ~120 cy on
//     the chain: VGPR=88 showed no prefetch buffer was kept).
//   - consumer: stores only (24 KB/tile, full 64B lines, b128 LDS reads).
//   - raw v_rcp_f32, no Newton (r9: absmax 16384 unchanged).
// Parallel-in-time (r6) is mathematically broken here (s ~ 20*EPS; EPS breaks
// the scale invariance) -- the serial chain stands.

constexpr int   T    = 2048;
constexpr int   B    = 8192;
constexpr int   RPB  = 32;        // rows per block
constexpr int   TT   = 64;        // steps per tile
constexpr int   NTI  = T / TT;    // 32 tiles
constexpr int   LSX  = 68;        // LDS stride words: 272B rows, 16B-aligned
constexpr float EPS  = 1e-8f;

__global__ __launch_bounds__(128, 1)
void hw_kernel(const float* __restrict__ x,
               const float* __restrict__ pla,
               const float* __restrict__ plg,
               float* __restrict__ out)
{
    __shared__ alignas(16) float LT[2][RPB][LSX];
    __shared__ alignas(16) float ST[2][RPB][LSX];
    __shared__ alignas(16) float YT[2][RPB][LSX];

    const int tid  = threadIdx.x;
    const int wid  = tid >> 6;        // 0 = producer, 1 = consumer
    const int lane = tid & 63;
    const int row0 = blockIdx.x * RPB;

    const float alpha = 1.0f / (1.0f + expf(-pla[0]));
    const float gamma = 1.0f / (1.0f + expf(-plg[0]));
    const float oma = 1.0f - alpha, omg = 1.0f - gamma;

    float* __restrict__ lout = out;
    float* __restrict__ sout = out + (size_t)B * T;
    float* __restrict__ yout = out + (size_t)2 * B * T;

    // store-phase lane mapping (both waves use it in the epilogue)
    const int cr = lane >> 4;          // 0..3
    const int cc = (lane & 15) << 2;   // 0,4,...,60

    auto store_tile = [&](int m, int itlo, int ithi) {
        const int bsel = m & 1;
        const int t0 = m * TT;
        for (int it = itlo; it < ithi; ++it) {
            const int r = 4 * it + cr;
            const size_t g = (size_t)(row0 + r) * T + t0 + cc;
            const float4 vl = *reinterpret_cast<const float4*>(&LT[bsel][r][cc]);
            const float4 vs = *reinterpret_cast<const float4*>(&ST[bsel][r][cc]);
            const float4 vy = *reinterpret_cast<const float4*>(&YT[bsel][r][cc]);
            *reinterpret_cast<float4*>(&lout[g]) = vl;
            *reinterpret_cast<float4*>(&sout[g]) = vs;
            *reinterpret_cast<float4*>(&yout[g]) = vy;
        }
    };

    if (wid == 0) {
        // ================= producer =================
        const bool act = lane < RPB;
        const float* __restrict__ xrow = x + (size_t)(row0 + (act ? lane : 0)) * T;

        float lp = 0.0f, sp = 1.0f;
        float4 XA[16], XB[16];

        auto loadX = [&](float4* Xb, int k) {
            const float* p = xrow + k * TT;
            #pragma unroll
            for (int i = 0; i < 16; ++i)
                Xb[i] = *reinterpret_cast<const float4*>(p + 4 * i);
        };

        auto do_step = [&](float xt, float& lo, float& so, float& yo) {
            const float rs = __builtin_amdgcn_rcpf(sp + EPS);
            const float lt = __builtin_fmaf(oma, lp, (alpha * xt) * rs);
            const float rl = __builtin_amdgcn_rcpf(lt + EPS);
            const float st = __builtin_fmaf(omg, sp, (gamma * xt) * rl);
            yo = xt * __builtin_amdgcn_rcpf(__builtin_fmaf(lt, st, EPS));
            lo = lt; so = st;
            lp = lt; sp = st;
        };

        auto compute_tile = [&](const float4* Xb, int k, bool first) {
            const int bsel = k & 1;
            #pragma unroll
            for (int g = 0; g < 16; ++g) {
                const float4 xv = Xb[g];
                float4 lv, sv, yv;
                if (first && g == 0) {
                    // t == 0: l0 = x0, s0 = 1, y0 = x0/(x0 + eps)
                    lv.x = xv.x; sv.x = 1.0f;
                    yv.x = xv.x * __builtin_amdgcn_rcpf(xv.x + EPS);
                    lp = xv.x; sp = 1.0f;
                    do_step(xv.y, lv.y, sv.y, yv.y);
                    do_step(xv.z, lv.z, sv.z, yv.z);
                    do_step(xv.w, lv.w, sv.w, yv.w);
                } else {
                    do_step(xv.x, lv.x, sv.x, yv.x);
                    do_step(xv.y, lv.y, sv.y, yv.y);
                    do_step(xv.z, lv.z, sv.z, yv.z);
                    do_step(xv.w, lv.w, sv.w, yv.w);
                }
                *reinterpret_cast<float4*>(&LT[bsel][lane][4 * g]) = lv;
                *reinterpret_cast<float4*>(&ST[bsel][lane][4 * g]) = sv;
                *reinterpret_cast<float4*>(&YT[bsel][lane][4 * g]) = yv;
            }
        };

        if (act) { loadX(XA, 0); loadX(XB, 1); }
        if (act) compute_tile(XA, 0, true);     // one-time vmcnt wait on XA
        __syncthreads();

        #pragma unroll 1
        for (int k = 1; k < NTI - 1; k += 2) {
            if (act) { loadX(XA, k + 1); compute_tile(XB, k, false); }
            __syncthreads();
            if (act) { loadX(XB, k + 2); compute_tile(XA, k + 1, false); }
            __syncthreads();
        }
        if (act) compute_tile(XB, NTI - 1, false);
        __syncthreads();
    } else {
        // ================= consumer: stores only =================
        #pragma unroll 1
        for (int k = 0; k < NTI; ++k) {
            if (k > 0) store_tile(k - 1, 0, 8);
            __syncthreads();
        }
    }

    // epilogue: tile 31 (buffer 1), both waves split the 8 store groups
    store_tile(NTI - 1, wid * 4, wid * 4 + 4);
}

extern "C" void kernel_launch(void* const* d_in, const int* in_sizes, int n_in,
                              void* d_out, int out_size, void* d_ws, size_t ws_size,
                              hipStream_t stream) {
    const float* x   = (const float*)d_in[0];
    const float* pla = (const float*)d_in[1];
    const float* plg = (const float*)d_in[2];
    float* out = (float*)d_out;

    dim3 grid(B / RPB);    // 256 blocks -> one producer/consumer pair per CU
    dim3 block(128);       // wave 0 = producer (32 rows), wave 1 = consumer
    hw_kernel<<<grid, block, 0, stream>>>(x, pla, plg, out);
}